// Round 1
// baseline (34.074 us; speedup 1.0000x reference)
//
#include <hip/hip_runtime.h>

// OpponentModelOracle: B=512, H=128, W=128, C=4 one-hot f32 input.
// Output: tuple (g_map [B,H,W] f32 with a single 1.0 per batch iff food exists,
//                zeros [B,H,W] f32), concatenated flat in d_out.

#define HW_CELLS 16384   // 128*128
#define W_DIM    128

__global__ __launch_bounds__(512)
void oracle_kernel(const float4* __restrict__ x,
                   float* __restrict__ out0,
                   float* __restrict__ out1) {
    const int b   = blockIdx.x;
    const int tid = threadIdx.x;

    __shared__ unsigned int foodmask[HW_CELLS / 32];  // 512 words, 2 KB
    __shared__ unsigned int opp_min;                   // first opponent flat idx
    __shared__ unsigned int key_min;                   // (sqdist<<14)|idx
    __shared__ unsigned int food_cnt;

    foodmask[tid] = 0u;  // blockDim.x == 512 == number of words
    if (tid == 0) {
        opp_min  = 0xFFFFFFFFu;
        key_min  = 0xFFFFFFFFu;
        food_cnt = 0u;
    }
    __syncthreads();

    const float4* xb = x + (size_t)b * HW_CELLS;

    // Phase 1: scan all cells (coalesced 16B/lane), build food bitmap + first-opp.
    for (int i = 0; i < HW_CELLS / 512; ++i) {
        const int cell = tid + i * 512;
        const float4 v = xb[cell];
        if (v.y == 1.0f) atomicOr(&foodmask[cell >> 5], 1u << (cell & 31));
        if (v.w == 1.0f) atomicMin(&opp_min, (unsigned)cell);
    }

    // Fused: zero both output maps (coalesced float4 stores).
    float4* o0 = reinterpret_cast<float4*>(out0 + (size_t)b * HW_CELLS);
    float4* o1 = reinterpret_cast<float4*>(out1 + (size_t)b * HW_CELLS);
    const float4 z = make_float4(0.f, 0.f, 0.f, 0.f);
    for (int i = 0; i < HW_CELLS / 4 / 512; ++i) {
        o0[tid + i * 512] = z;
        o1[tid + i * 512] = z;
    }

    __syncthreads();

    // First opponent (argmax over booleans: 0 if none) -> coords.
    unsigned opp = opp_min;
    if (opp == 0xFFFFFFFFu) opp = 0u;
    const int opp_r = (int)(opp >> 7);
    const int opp_c = (int)(opp & (W_DIM - 1));

    // Phase 2: each thread owns one bitmap word; popcount + per-food-cell key.
    unsigned m   = foodmask[tid];
    const int cnt = __popc(m);
    unsigned local_key = 0xFFFFFFFFu;
    while (m) {
        const int bit = __ffs(m) - 1;
        m &= m - 1u;
        const int idx = (tid << 5) | bit;
        const int r = idx >> 7;
        const int c = idx & (W_DIM - 1);
        const int dr = r - opp_r;
        const int dc = c - opp_c;
        const unsigned sq = (unsigned)(dr * dr + dc * dc);   // <= 32258 < 2^15
        const unsigned key = (sq << 14) | (unsigned)idx;     // idx < 2^14
        if (key < local_key) local_key = key;
    }
    if (local_key != 0xFFFFFFFFu) atomicMin(&key_min, local_key);
    if (cnt) atomicAdd(&food_cnt, (unsigned)cnt);

    __syncthreads();

    // Phase 3: apply placement policy, single write.
    if (tid == 0) {
        const unsigned fc = food_cnt;
        if (fc > 0u) {
            const unsigned min_idx = key_min & 16383u;
            const bool opp_at_start = (opp_r == 3) && (opp_c == 6);
            const bool use_min = (fc == 1u) || (fc > 1u && !opp_at_start);
            const unsigned tgt = use_min ? min_idx : 0u;
            out0[(size_t)b * HW_CELLS + tgt] = 1.0f;
        }
    }
}

extern "C" void kernel_launch(void* const* d_in, const int* in_sizes, int n_in,
                              void* d_out, int out_size, void* d_ws, size_t ws_size,
                              hipStream_t stream) {
    const float4* x = (const float4*)d_in[0];
    float* out = (float*)d_out;
    const int B = 512;
    float* out0 = out;                         // g_map
    float* out1 = out + (size_t)B * HW_CELLS;  // zeros_like(g_map)

    oracle_kernel<<<B, 512, 0, stream>>>(x, out0, out1);
}